// Round 8
// baseline (118600.232 us; speedup 1.0000x reference)
//
#include <hip/hip_runtime.h>
#include <hip/hip_bf16.h>

typedef unsigned short u16;

// ---------------- constants ----------------
// B=64, T=512, C=512, H=512, D=80, RF=2, PRE_IN=160, PRE_INNER=256, CONV_CH=32, K=31

__device__ __forceinline__ float b2f(u16 u) {
  return __uint_as_float(((unsigned)u) << 16);
}
__device__ __forceinline__ u16 f2b(float f) {   // RNE f32->bf16
  unsigned u = __float_as_uint(f);
  u += 0x7fffu + ((u >> 16) & 1u);
  return (u16)(u >> 16);
}
template<bool F32>
__device__ __forceinline__ float ldw(const void* p, size_t i) {
  return F32 ? ((const float*)p)[i] : b2f(((const u16*)p)[i]);
}
template<bool F32>
__device__ __forceinline__ float4 ldw4(const void* p, size_t i) {
  if (F32) {
    return *(const float4*)((const float*)p + i);
  } else {
    uint2 u = *(const uint2*)((const u16*)p + i);
    float4 r;
    r.x = __uint_as_float(u.x << 16);
    r.y = __uint_as_float(u.x & 0xffff0000u);
    r.z = __uint_as_float(u.y << 16);
    r.w = __uint_as_float(u.y & 0xffff0000u);
    return r;
  }
}
template<bool F32>
__device__ __forceinline__ void stout(void* p, size_t i, float v) {
  if (F32) ((float*)p)[i] = v; else ((u16*)p)[i] = f2b(v);
}
__device__ __forceinline__ float frcp(float x) { return __builtin_amdgcn_rcpf(x); }
__device__ __forceinline__ float tanh_f(float x) {
  float e = __expf(2.f * x);
  return 1.f - 2.f * frcp(e + 1.f);     // inf-safe
}
__device__ __forceinline__ float sig_f(float x) { return frcp(1.f + __expf(-x)); }

// ---- relaxed agent-scope (MALL-coherent, fence-free) accessors ----
__device__ __forceinline__ void st_sc(int* p, int v) {
  __hip_atomic_store(p, v, __ATOMIC_RELAXED, __HIP_MEMORY_SCOPE_AGENT);
}
__device__ __forceinline__ int ld_sc(const int* p) {
  return __hip_atomic_load(p, __ATOMIC_RELAXED, __HIP_MEMORY_SCOPE_AGENT);
}
__device__ __forceinline__ void stf_sc(float* p, float v) {
  __hip_atomic_store(p, v, __ATOMIC_RELAXED, __HIP_MEMORY_SCOPE_AGENT);
}
__device__ __forceinline__ float ldf_sc(const float* p) {
  return __hip_atomic_load(p, __ATOMIC_RELAXED, __HIP_MEMORY_SCOPE_AGENT);
}

// Burst-copy n floats global->LDS; 512-thread, 16 loads in flight.
__device__ __forceinline__ void stage_n(float* lds, const float* src, int n, int tid) {
  int i = 0;
  for (; i + 8192 <= n; i += 8192) {
    float r[16];
#pragma unroll
    for (int j = 0; j < 16; ++j) r[j] = ldf_sc(src + i + tid + j * 512);
#pragma unroll
    for (int j = 0; j < 16; ++j) lds[i + tid + j * 512] = r[j];
  }
  for (; i < n; i += 2048) {
    float r[4];
#pragma unroll
    for (int j = 0; j < 4; ++j) r[j] = ldf_sc(src + i + tid + j * 512);
#pragma unroll
    for (int j = 0; j < 4; ++j) lds[i + tid + j * 512] = r[j];
  }
}
// Burst-copy sum of two arrays global->LDS.
__device__ __forceinline__ void stage_sum2(float* lds, const float* a, const float* b,
                                           int n, int tid) {
  int i = 0;
  for (; i + 8192 <= n; i += 8192) {
    float r[8], s[8];
#pragma unroll
    for (int j = 0; j < 8; ++j) { r[j] = ldf_sc(a + i + tid + j * 512); }
#pragma unroll
    for (int j = 0; j < 8; ++j) { s[j] = ldf_sc(b + i + tid + j * 512); }
#pragma unroll
    for (int j = 0; j < 8; ++j) lds[i + tid + j * 512] = r[j] + s[j];
    i += 4096;   // processed 4096 above? no — see below
    i -= 4096;
    // second half of the 8192 block
#pragma unroll
    for (int j = 0; j < 8; ++j) { r[j] = ldf_sc(a + i + 4096 + tid + j * 512); }
#pragma unroll
    for (int j = 0; j < 8; ++j) { s[j] = ldf_sc(b + i + 4096 + tid + j * 512); }
#pragma unroll
    for (int j = 0; j < 8; ++j) lds[i + 4096 + tid + j * 512] = r[j] + s[j];
  }
  for (; i < n; i += 2048) {
    float r[4], s[4];
#pragma unroll
    for (int j = 0; j < 4; ++j) r[j] = ldf_sc(a + i + tid + j * 512);
#pragma unroll
    for (int j = 0; j < 4; ++j) s[j] = ldf_sc(b + i + tid + j * 512);
#pragma unroll
    for (int j = 0; j < 4; ++j) lds[i + tid + j * 512] = r[j] + s[j];
  }
}

// ---- software-pipelined weight-streaming dot kernel ----
template<bool F32, int NR>
__device__ __forceinline__ void dotN(float* __restrict__ acc, const float* __restrict__ sb,
                                     const void* __restrict__ wb, size_t rb, int wstride,
                                     int nk, int lane, int vz) {
  float4 wa[NR], wn[NR];
#pragma unroll
  for (int i = 0; i < NR; ++i) wa[i] = ldw4<F32>(wb, rb + (size_t)i * wstride + vz);
  for (int kg = 0; kg < nk; kg += 8) {
#pragma unroll
    for (int i = 0; i < NR; ++i) wn[i] = ldw4<F32>(wb, rb + (size_t)i * wstride + kg + 4 + vz);
    float a0 = sb[(kg + 0) * 64 + lane], a1 = sb[(kg + 1) * 64 + lane],
          a2 = sb[(kg + 2) * 64 + lane], a3 = sb[(kg + 3) * 64 + lane];
#pragma unroll
    for (int i = 0; i < NR; ++i)
      acc[i] = fmaf(wa[i].w, a3, fmaf(wa[i].z, a2, fmaf(wa[i].y, a1, fmaf(wa[i].x, a0, acc[i]))));
    int kn = (kg + 8 < nk) ? kg + 8 : kg;
#pragma unroll
    for (int i = 0; i < NR; ++i) wa[i] = ldw4<F32>(wb, rb + (size_t)i * wstride + kn + vz);
    float b0 = sb[(kg + 4) * 64 + lane], b1 = sb[(kg + 5) * 64 + lane],
          b2 = sb[(kg + 6) * 64 + lane], b3 = sb[(kg + 7) * 64 + lane];
#pragma unroll
    for (int i = 0; i < NR; ++i)
      acc[i] = fmaf(wn[i].w, b3, fmaf(wn[i].z, b2, fmaf(wn[i].y, b1, fmaf(wn[i].x, b0, acc[i]))));
  }
}

// ---------------- ws layout (float offsets), ~44.8 MB ----------------
constexpr size_t OBAR  = 0;                       // [32]=gen, [64]=dtype flag
constexpr size_t OFLG  = OBAR  + 128;             // per-wg arrival flags 512*32 ints
constexpr size_t OASUM = OFLG  + 16384;           // att_sum [b][t]     32768
constexpr size_t ODEC  = OASUM + 32768;           // dec partials [4][b][h]  131072
constexpr size_t OH0   = ODEC  + 131072;          // h0T    [h][b]      32768
constexpr size_t OH1   = OH0   + 32768;           // h1T    [h][b]      32768
constexpr size_t OPO   = OH1   + 32768;           // poT0,poT1 [n][b]   20480
constexpr size_t OZEND = OPO   + 20480;
constexpr int    ZERO_SPAN_N = (int)OZEND;
constexpr size_t OPRV  = OZEND;                   // prev_w [b][t]      32768
constexpr size_t OERG  = OPRV  + 32768;           // erg    [b][t]      32768
constexpr size_t OX1   = OERG  + 32768;           // x1T    [n][b]      16384
constexpr size_t OX2   = OX1   + 16384;           // x2T    [n][b]      32768
constexpr size_t OATTC = OX2   + 32768;           // attcT  [c][b]      32768
constexpr size_t OATC2 = OATTC + 32768;           // attc2  [c][b]      32768
constexpr size_t OMM   = OATC2 + 32768;           // M[h][32] f32       16384
constexpr size_t OGI0  = OMM   + 16384;           // gi0p [8][1536][64] 786432 (setup alias: encT)
constexpr size_t OGH0  = OGI0  + 786432;          // gh0p [4][1536][64] 393216
constexpr size_t OGH1  = OGH0  + 393216;          // gh1p [4][1536][64] 393216
constexpr size_t OGI1  = OGH1  + 393216;          // gi1p [8][1536][64] 786432
constexpr size_t OPM   = OGI1  + 786432;          // pm bf16 (16.7M u16 = 8388608 slots)
constexpr size_t OTOT  = OPM   + 8388608;

// ---------------- fence-free flag barrier (512 wgs) ----------------
__device__ __forceinline__ void fastbar(int* flags, int* gen, int target,
                                        int wg, int tid) {
  __syncthreads();
  if (tid == 0) st_sc(flags + wg * 32, target);
  if (wg == 0) {
    if (tid < 128) {
      int i0 = tid * 4;
      for (;;) {
        int ok = (ld_sc(flags + (i0 + 0) * 32) >= target)
               & (ld_sc(flags + (i0 + 1) * 32) >= target)
               & (ld_sc(flags + (i0 + 2) * 32) >= target)
               & (ld_sc(flags + (i0 + 3) * 32) >= target);
        if (__ballot(ok) == 0xFFFFFFFFFFFFFFFFull) break;
      }
      __syncthreads();
      if (tid == 0) st_sc(gen, target);
    } else {
      __syncthreads();
    }
    __syncthreads();
  } else {
    if (tid == 0) {
      while (ld_sc(gen) < target) {}
    }
    __syncthreads();
  }
}

// ---------------- setup kernels (256 threads) ----------------
__global__ void k_zero(float* p, int n) {
  for (int i = blockIdx.x * 256 + threadIdx.x; i < n; i += gridDim.x * 256) p[i] = 0.f;
}
__global__ void k_detect(int* flag, const u16* probe) {
  if (blockIdx.x != 0 || threadIdx.x != 0) return;
  int sane = 0;
  for (int i = 0; i < 256; i += 2) {
    u16 u = probe[i];
    int e = (u >> 7) & 0xFF;
    if (u == 0 || (e >= 97 && e <= 140)) ++sane;
  }
  *flag = (sane < 96) ? 1 : 0;   // 1 => inputs are raw f32
}
__global__ void k_prevw(float* prevw, const int* dlen) {
  int b = blockIdx.x;
  int len = dlen[b] >> 1;
  float inv = 1.f / (float)len;
  for (int i = threadIdx.x; i < 512; i += 256)
    prevw[b * 512 + i] = (i < len) ? inv : 0.f;
}
template<bool F32>
__global__ void k_cvtT512(const int* flag, float* dst, const void* src) {
  if (*flag != (F32 ? 1 : 0)) return;
  for (int i = blockIdx.x * 256 + threadIdx.x; i < 262144; i += gridDim.x * 256) {
    int c = i >> 9, h = i & 511;
    dst[i] = ldw<F32>(src, (size_t)h * 512 + c);
  }
}
template<bool F32>
__global__ void k_mmat(const int* flag, float* M, const void* locw, const void* convw) {
  if (*flag != (F32 ? 1 : 0)) return;
  int i = blockIdx.x * 256 + threadIdx.x;
  if (i >= 16384) return;
  int h = i >> 5, k = i & 31;
  float acc = 0.f;
  if (k < 31) {
    for (int c = 0; c < 32; ++c)
      acc = fmaf(ldw<F32>(locw, h * 32 + c), ldw<F32>(convw, c * 31 + k), acc);
  }
  M[i] = acc;
}
template<bool F32>
__global__ __launch_bounds__(256) void k_pm(const int* flag, u16* pm, const void* enc,
                                            const float* encwT, const void* encb) {
  if (*flag != (F32 ? 1 : 0)) return;
  __shared__ float encf[16 * 512];
  int row0 = blockIdx.x * 16;
  int tid = threadIdx.x;
  for (int i = tid; i < 16 * 512; i += 256) {
    int r = i >> 9, c = i & 511;
    encf[i] = ldw<F32>(enc, (size_t)(row0 + r) * 512 + c);
  }
  __syncthreads();
  float a0[16], a1[16];
  float bb0 = ldw<F32>(encb, tid), bb1 = ldw<F32>(encb, tid + 256);
#pragma unroll
  for (int r = 0; r < 16; ++r) { a0[r] = bb0; a1[r] = bb1; }
  for (int c = 0; c < 512; ++c) {
    float w0 = encwT[c * 512 + tid];
    float w1 = encwT[c * 512 + 256 + tid];
#pragma unroll
    for (int r = 0; r < 16; ++r) {
      float a = encf[r * 512 + c];
      a0[r] = fmaf(w0, a, a0[r]);
      a1[r] = fmaf(w1, a, a1[r]);
    }
  }
#pragma unroll
  for (int r = 0; r < 16; ++r) {
    pm[(size_t)(row0 + r) * 512 + tid]       = f2b(a0[r]);
    pm[(size_t)(row0 + r) * 512 + 256 + tid] = f2b(a1[r]);
  }
}

// ---------------- main persistent kernel (512 wgs x 512 thr, 2 wg/CU) ----------------
struct KP {
  const void* __restrict__ enc;
  const int* __restrict__ dlen;
  const u16* __restrict__ pm;          // internal bf16
  const void* __restrict__ wih0; const void* __restrict__ whh0;
  const void* __restrict__ wih1; const void* __restrict__ whh1;
  const void* __restrict__ adec; const void* __restrict__ outw;
  const void* __restrict__ pnw2; const void* __restrict__ pnw1;
  const void* __restrict__ pnb1; const void* __restrict__ pnb2;
  const void* __restrict__ bih0; const void* __restrict__ bhh0;
  const void* __restrict__ bih1; const void* __restrict__ bhh1;
  const void* __restrict__ outb; const void* __restrict__ vw;
  const float* __restrict__ Mg;
  int* __restrict__ bar;               // [32]=gen, [64]=dtype
  int* __restrict__ flags;             // 512 * 32 ints
  float* __restrict__ asum; float* __restrict__ decp;   // decp: 4 partials
  float* __restrict__ h0T;  float* __restrict__ h1T;
  float* __restrict__ poT0; float* __restrict__ poT1;
  float* __restrict__ prevw; float* __restrict__ erg;
  float* __restrict__ x1T;  float* __restrict__ x2T;
  float* __restrict__ attcT; float* __restrict__ attc2;
  float* __restrict__ gi0p; float* __restrict__ gh0p;
  float* __restrict__ gh1p; float* __restrict__ gi1p;
  void* __restrict__ out;              // out_o at elem 0; out_a at elem 5242880
};

template<bool F32>
__global__ __launch_bounds__(512, 4) void k_loop(KP p) {
  if (*(const volatile int*)(p.bar + 64) != (F32 ? 1 : 0)) return;  // wrong-dtype variant exits
  __shared__ float stg[8192];        // 32 KB staging buffer
  __shared__ u16  M_u[32 * 512];
  __shared__ float dec_s[512];
  __shared__ float v_s[512];
  __shared__ float wq[96];
  __shared__ float sm[512];
  __shared__ float red[16];

  const int wg = blockIdx.x, tid = threadIdx.x;
  const int lane = tid & 63;
  const int wv = __builtin_amdgcn_readfirstlane(tid >> 6);   // 0..7
  const int b_att = wg >> 3, oct = wg & 7, t0 = oct * 64;
  const int trow = tid >> 6;          // 0..7 (= wv)
  const int hcol = tid & 63;
  int* genp = p.bar + 32;
  int bt = 0;
  int vz;                            // opaque VGPR zero: forces VMEM path for weights
  asm volatile("v_mov_b32 %0, 0" : "=v"(vz));

  for (int i = tid; i < 32 * 512; i += 512) {
    int k = i >> 9, h = i & 511;
    M_u[i] = f2b(p.Mg[h * 32 + k]);
  }
  if (tid < 512) v_s[tid] = ldw<F32>(p.vw, tid);
  __syncthreads();

  for (int t = 0; t < 512; ++t) {
    // ===== S1: attention energies (all wgs) + prenet-1 (wgs 0-31) + deferred out_o store =====
    if (wg < 32) stage_sum2(stg, p.poT0, p.poT1, 8192, tid);   // poT rows 0-127 summed
    if (tid < 94) {
      int g = t0 - 15 + tid;
      wq[tid] = (g >= 0 && g < 512) ? ldf_sc(p.prevw + b_att * 512 + g) : 0.f;
    }
    dec_s[tid] = ldf_sc(p.decp + b_att * 512 + tid)
               + ldf_sc(p.decp + 32768 + b_att * 512 + tid)
               + ldf_sc(p.decp + 65536 + b_att * 512 + tid)
               + ldf_sc(p.decp + 98304 + b_att * 512 + tid);
    __syncthreads();
    float pacc[1] = {0.f};
    int pn = wg * 8 + wv;            // prenet-1 output index (wg<32)
    if (wg < 32) {
      if (wg == 0 && t > 0) {
        for (int i = tid; i < 8192; i += 512) {
          int r = i >> 6, b = i & 63;
          stout<F32>(p.out, (size_t)b * 81920 + (size_t)(r >> 1) * 1024 + (t - 1) * 2 + (r & 1), stg[i]);
        }
      }
      dotN<F32, 1>(pacc, stg, p.pnw1, (size_t)pn * 160, 160, 128, lane, vz);
    }
    {
      // each wave owns 8 s-rows: s = trow*8 .. +8
      float wreg[38];
#pragma unroll
      for (int i = 0; i < 38; ++i) wreg[i] = wq[trow * 8 + i];
      float acc[8];
#pragma unroll
      for (int s = 0; s < 8; ++s) acc[s] = 0.f;
      const u16* pmb = p.pm + ((size_t)(b_att * 512 + t0 + trow * 8)) * 512;
      for (int j = 0; j < 8; ++j) {
        int hj = hcol + 64 * j;
        float Mreg[31];
#pragma unroll
        for (int k = 0; k < 31; ++k) Mreg[k] = b2f(M_u[k * 512 + hj]);
        float dj = dec_s[hj], vj = v_s[hj];
#pragma unroll
        for (int s = 0; s < 8; ++s) {
          float u = dj;
#pragma unroll
          for (int k = 0; k < 31; ++k) u = fmaf(Mreg[k], wreg[s + k], u);
          u += b2f(pmb[s * 512 + hj]);
          acc[s] = fmaf(vj, tanh_f(u), acc[s]);
        }
      }
#pragma unroll
      for (int s = 0; s < 8; ++s) {
        float v = acc[s];
#pragma unroll
        for (int off = 32; off; off >>= 1) v += __shfl_xor(v, off, 64);
        if (hcol == 0) sm[trow * 8 + s] = v;
      }
      __syncthreads();
      if (tid < 64) stf_sc(p.erg + b_att * 512 + t0 + tid, sm[tid]);
    }
    if (wg < 32) {
      stage_sum2(stg, p.poT0 + 8192, p.poT1 + 8192, 2048, tid);   // poT rows 128-159
      __syncthreads();
      if (wg == 0 && t > 0) {
        for (int i = tid; i < 2048; i += 512) {
          int r = 128 + (i >> 6), b = i & 63;
          stout<F32>(p.out, (size_t)b * 81920 + (size_t)(r >> 1) * 1024 + (t - 1) * 2 + (r & 1), stg[i]);
        }
      }
      dotN<F32, 1>(pacc, stg, p.pnw1, (size_t)pn * 160 + 128, 160, 32, lane, vz);
      stf_sc(p.x1T + pn * 64 + lane, fmaxf(pacc[0] + ldw<F32>(p.pnb1, pn), 0.f));
    }
    fastbar(p.flags, genp, ++bt, wg, tid);

    // ===== S2: softmax/out_a (64) | att_c partials (256) | prenet-2 (64) =====
    if (wg < 64) {
      int b = wg;
      int len = p.dlen[b] >> 1;
      float e0 = ldf_sc(p.erg + b * 512 + tid);
      bool v0 = tid < len;
      float mx = v0 ? e0 : -1e30f;
#pragma unroll
      for (int off = 32; off; off >>= 1) mx = fmaxf(mx, __shfl_xor(mx, off, 64));
      if (lane == 0) red[wv] = mx;
      __syncthreads();
      mx = fmaxf(fmaxf(fmaxf(red[0], red[1]), fmaxf(red[2], red[3])),
                 fmaxf(fmaxf(red[4], red[5]), fmaxf(red[6], red[7])));
      float x0 = v0 ? __expf(e0 - mx) : 0.f;
      float s = x0;
#pragma unroll
      for (int off = 32; off; off >>= 1) s += __shfl_xor(s, off, 64);
      if (lane == 0) red[8 + wv] = s;
      __syncthreads();
      s = ((red[8] + red[9]) + (red[10] + red[11])) + ((red[12] + red[13]) + (red[14] + red[15]));
      float w0 = x0 * frcp(s);
      stout<F32>(p.out, 5242880 + (size_t)b * 262144 + (size_t)tid * 512 + t, w0);
      float s0 = p.asum[b * 512 + tid] + w0;
      p.asum[b * 512 + tid] = s0;
      stf_sc(p.prevw + b * 512 + tid, s0);
    } else if (wg < 320) {
      int idx = wg - 64, b = idx >> 2, quad = idx & 3, half = quad & 1, tpart = quad >> 1;
      int len = p.dlen[b] >> 1;
      float e0 = ldf_sc(p.erg + b * 512 + tid);
      bool v0 = tid < len;
      float mx = v0 ? e0 : -1e30f;
#pragma unroll
      for (int off = 32; off; off >>= 1) mx = fmaxf(mx, __shfl_xor(mx, off, 64));
      if (lane == 0) red[wv] = mx;
      __syncthreads();
      mx = fmaxf(fmaxf(fmaxf(red[0], red[1]), fmaxf(red[2], red[3])),
                 fmaxf(fmaxf(red[4], red[5]), fmaxf(red[6], red[7])));
      float x0 = v0 ? __expf(e0 - mx) : 0.f;
      float s = x0;
#pragma unroll
      for (int off = 32; off; off >>= 1) s += __shfl_xor(s, off, 64);
      if (lane == 0) red[8 + wv] = s;
      __syncthreads();
      s = ((red[8] + red[9]) + (red[10] + red[11])) + ((red[12] + red[13]) + (red[14] + red[15]));
      sm[tid] = x0 * frcp(s);
      __syncthreads();
      // lane owns 4 consecutive channels; wave owns 32 taus of its tau-half; 16 chains
      int c4 = half * 256 + lane * 4;
      size_t eb = (size_t)b * 262144 + c4;
      float4 ac[16];
#pragma unroll
      for (int i = 0; i < 16; ++i) ac[i] = make_float4(0.f, 0.f, 0.f, 0.f);
      int tb = tpart * 256 + wv * 32;
      for (int tt = 0; tt < 32; tt += 16) {
#pragma unroll
        for (int i = 0; i < 16; ++i) {
          float4 e = ldw4<F32>(p.enc, eb + (size_t)(tb + tt + i) * 512);
          float w = sm[tb + tt + i];
          ac[i].x = fmaf(w, e.x, ac[i].x);
          ac[i].y = fmaf(w, e.y, ac[i].y);
          ac[i].z = fmaf(w, e.z, ac[i].z);
          ac[i].w = fmaf(w, e.w, ac[i].w);
        }
      }
      float4 ssum; ssum.x = 0.f; ssum.y = 0.f; ssum.z = 0.f; ssum.w = 0.f;
#pragma unroll
      for (int i = 0; i < 16; ++i) {
        ssum.x += ac[i].x; ssum.y += ac[i].y; ssum.z += ac[i].z; ssum.w += ac[i].w;
      }
      __syncthreads();
      *(float4*)&stg[wv * 256 + lane * 4] = ssum;   // 8 wave-partials x 256 ch
      __syncthreads();
      if (tid < 256) {
        float r = ((stg[tid] + stg[256 + tid]) + (stg[512 + tid] + stg[768 + tid]))
                + ((stg[1024 + tid] + stg[1280 + tid]) + (stg[1536 + tid] + stg[1792 + tid]));
        stf_sc((tpart ? p.attc2 : p.attcT) + (half * 256 + tid) * 64 + b, r);
      }
    } else if (wg < 384) {
      int n = (wg - 320) * 8 + wv;
      float a[1] = {0.f};
      for (int c = 0; c < 2; ++c) {
        stage_n(stg, p.x1T + c * 8192, 8192, tid);
        __syncthreads();
        dotN<F32, 1>(a, stg, p.pnw2, (size_t)n * 256 + c * 128, 256, 128, lane, vz);
        __syncthreads();
      }
      stf_sc(p.x2T + n * 64 + lane, fmaxf(a[0] + ldw<F32>(p.pnb2, n), 0.f));
    }
    fastbar(p.flags, genp, ++bt, wg, tid);

    // ===== S3: gi0 (256, 8 kparts) | gh0 (128, 4 kparts) | gh1 (128, 4 kparts) =====
    {
      const float* srcA; const float* srcB = nullptr; const void* wb; float* dst;
      int n0, wstride, wc0;
      if (wg < 256) {               // gi0: K=1024 in 8 parts of 128
        int kpart = wg & 7, ngrp = wg >> 3;
        if (kpart < 4) srcA = p.x2T + kpart * 8192;
        else { srcA = p.attcT + (kpart - 4) * 8192; srcB = p.attc2 + (kpart - 4) * 8192; }
        wb = p.wih0; wstride = 1024; wc0 = kpart * 128;
        n0 = ngrp * 48 + wv * 6;
        dst = p.gi0p + ((size_t)kpart * 1536 + n0) * 64;
      } else if (wg < 384) {        // gh0: K=512 in 4 parts of 128
        int idx = wg - 256, kpart = idx & 3, ngrp = idx >> 2;
        srcA = p.h0T + kpart * 8192;
        wb = p.whh0; wstride = 512; wc0 = kpart * 128;
        n0 = ngrp * 48 + wv * 6;
        dst = p.gh0p + ((size_t)kpart * 1536 + n0) * 64;
      } else {                      // gh1
        int idx = wg - 384, kpart = idx & 3, ngrp = idx >> 2;
        srcA = p.h1T + kpart * 8192;
        wb = p.whh1; wstride = 512; wc0 = kpart * 128;
        n0 = ngrp * 48 + wv * 6;
        dst = p.gh1p + ((size_t)kpart * 1536 + n0) * 64;
      }
      if (srcB) stage_sum2(stg, srcA, srcB, 8192, tid);
      else stage_n(stg, srcA, 8192, tid);
      __syncthreads();
      float acc[6];
#pragma unroll
      for (int i = 0; i < 6; ++i) acc[i] = 0.f;
      dotN<F32, 6>(acc, stg, wb, (size_t)n0 * wstride + wc0, wstride, 128, lane, vz);
#pragma unroll
      for (int i = 0; i < 6; ++i) stf_sc(dst + (size_t)i * 64 + lane, acc[i]);
    }
    fastbar(p.flags, genp, ++bt, wg, tid);

    // ===== S4: GRU0 combine -> h0' =====
    if (wg < 64) {
      int e = wg * 512 + tid;
      int h = e >> 6, b = e & 63;
      float ir = ldw<F32>(p.bih0, h), iz = ldw<F32>(p.bih0, 512 + h), in = ldw<F32>(p.bih0, 1024 + h);
#pragma unroll
      for (int c = 0; c < 8; ++c) {
        ir += ldf_sc(p.gi0p + ((size_t)c * 1536 + h) * 64 + b);
        iz += ldf_sc(p.gi0p + ((size_t)c * 1536 + 512 + h) * 64 + b);
        in += ldf_sc(p.gi0p + ((size_t)c * 1536 + 1024 + h) * 64 + b);
      }
      float hr = ldw<F32>(p.bhh0, h), hz = ldw<F32>(p.bhh0, 512 + h), hn = ldw<F32>(p.bhh0, 1024 + h);
#pragma unroll
      for (int c = 0; c < 4; ++c) {
        hr += ldf_sc(p.gh0p + ((size_t)c * 1536 + h) * 64 + b);
        hz += ldf_sc(p.gh0p + ((size_t)c * 1536 + 512 + h) * 64 + b);
        hn += ldf_sc(p.gh0p + ((size_t)c * 1536 + 1024 + h) * 64 + b);
      }
      float r = sig_f(ir + hr), z = sig_f(iz + hz);
      float nn = tanh_f(in + r * hn);
      float ho = ldf_sc(p.h0T + h * 64 + b);
      stf_sc(p.h0T + h * 64 + b, (1.f - z) * nn + z * ho);
    }
    fastbar(p.flags, genp, ++bt, wg, tid);

    // ===== S5: gi1 (256, 8 kparts of 64) | dec partials (256, 4 cparts) =====
    if (wg < 256) {
      int kpart = wg & 7, ngrp = wg >> 3;
      stage_n(stg, p.h0T + kpart * 4096, 4096, tid);
      __syncthreads();
      int n0 = ngrp * 48 + wv * 6;
      float acc[6];
#pragma unroll
      for (int i = 0; i < 6; ++i) acc[i] = 0.f;
      dotN<F32, 6>(acc, stg, p.wih1, (size_t)n0 * 512 + kpart * 64, 512, 64, lane, vz);
#pragma unroll
      for (int i = 0; i < 6; ++i)
        stf_sc(p.gi1p + ((size_t)kpart * 1536 + n0 + i) * 64 + lane, acc[i]);
    } else {
      int g = wg - 256;
      int cpart = g >> 6;
      int n = (g & 63) * 8 + wv;
      stage_n(stg, p.h0T + cpart * 8192, 8192, tid);
      __syncthreads();
      float r[1] = {0.f};
      dotN<F32, 1>(r, stg, p.adec, (size_t)n * 512 + cpart * 128, 512, 128, lane, vz);
      stf_sc(p.decp + (size_t)cpart * 32768 + lane * 512 + n, r[0]);
    }
    fastbar(p.flags, genp, ++bt, wg, tid);

    // ===== S6: GRU1 combine -> h1' =====
    if (wg < 64) {
      int e = wg * 512 + tid;
      int h = e >> 6, b = e & 63;
      float ir = ldw<F32>(p.bih1, h), iz = ldw<F32>(p.bih1, 512 + h), in = ldw<F32>(p.bih1, 1024 + h);
#pragma unroll
      for (int c = 0; c < 8; ++c) {
        ir += ldf_sc(p.gi1p + ((size_t)c * 1536 + h) * 64 + b);
        iz += ldf_sc(p.gi1p + ((size_t)c * 1536 + 512 + h) * 64 + b);
        in += ldf_sc(p.gi1p + ((size_t)c * 1536 + 1024 + h) * 64 + b);
      }
      float hr = ldw<F32>(p.bhh1, h), hz = ldw<F32>(p.bhh1, 512 + h), hn = ldw<F32>(p.bhh1, 1024 + h);
#pragma unroll
      for (int c = 0; c < 4; ++c) {
        hr += ldf_sc(p.gh1p + ((size_t)c * 1536 + h) * 64 + b);
        hz += ldf_sc(p.gh1p + ((size_t)c * 1536 + 512 + h) * 64 + b);
        hn += ldf_sc(p.gh1p + ((size_t)c * 1536 + 1024 + h) * 64 + b);
      }
      float r = sig_f(ir + hr), z = sig_f(iz + hz);
      float nn = tanh_f(in + r * hn);
      float ho = ldf_sc(p.h1T + h * 64 + b);
      stf_sc(p.h1T + h * 64 + b, (1.f - z) * nn + z * ho);
    }
    fastbar(p.flags, genp, ++bt, wg, tid);

    // ===== S7: out partials — kpart0: h1 half (wgs 0-19), kpart1: attc half (wgs 20-39) =====
    if (wg < 40) {
      int kp = wg / 20;
      int n = (wg % 20) * 8 + wv;
      float r[1] = {0.f};
      for (int c = 0; c < 4; ++c) {
        if (kp == 0) stage_n(stg, p.h1T + c * 8192, 8192, tid);
        else stage_sum2(stg, p.attcT + c * 8192, p.attc2 + c * 8192, 8192, tid);
        __syncthreads();
        dotN<F32, 1>(r, stg, p.outw, (size_t)n * 1024 + kp * 512 + c * 128, 1024, 128, lane, vz);
        __syncthreads();
      }
      float acc = r[0] + (kp ? ldw<F32>(p.outb, n) : 0.f);
      stf_sc((kp ? p.poT1 : p.poT0) + n * 64 + lane, acc);
    }
    fastbar(p.flags, genp, ++bt, wg, tid);
  }

  // ===== epilogue: store out_o for t=511 =====
  if (wg == 0) {
    stage_sum2(stg, p.poT0, p.poT1, 8192, tid);
    __syncthreads();
    for (int i = tid; i < 8192; i += 512) {
      int r = i >> 6, b = i & 63;
      stout<F32>(p.out, (size_t)b * 81920 + (size_t)(r >> 1) * 1024 + 511 * 2 + (r & 1), stg[i]);
    }
    __syncthreads();
    stage_sum2(stg, p.poT0 + 8192, p.poT1 + 8192, 2048, tid);
    __syncthreads();
    for (int i = tid; i < 2048; i += 512) {
      int r = 128 + (i >> 6), b = i & 63;
      stout<F32>(p.out, (size_t)b * 81920 + (size_t)(r >> 1) * 1024 + 511 * 2 + (r & 1), stg[i]);
    }
  }
}

// ---------------- host launcher ----------------
extern "C" void kernel_launch(void* const* d_in, const int* in_sizes, int n_in,
                              void* d_out, int out_size, void* d_ws, size_t ws_size,
                              hipStream_t stream) {
  (void)in_sizes; (void)n_in; (void)out_size; (void)ws_size;
  const void* enc   = d_in[0];
  const int*  dlen  = (const int*)d_in[1];
  const void* pnw1  = d_in[2];
  const void* pnb1  = d_in[3];
  const void* pnw2  = d_in[4];
  const void* pnb2  = d_in[5];
  const void* aencw = d_in[6];
  const void* aencb = d_in[7];
  const void* adecw = d_in[8];
  const void* aconv = d_in[9];
  const void* alocw = d_in[10];
  const void* avw   = d_in[11];
  // d_in[12] = att_v_b: softmax-invariant -> unused
  const void* wih0  = d_in[13];
  const void* whh0  = d_in[14];
  const void* bih0  = d_in[15];
  const void* bhh0  = d_in[16];
  const void* wih1  = d_in[17];
  const void* whh1  = d_in[18];
  const void* bih1  = d_in[19];
  const void* bhh1  = d_in[20];
  const void* outw  = d_in[21];
  const void* outb  = d_in[22];

  float* W = (float*)d_ws;
  int* flag = (int*)(W + OBAR) + 64;
  dim3 blk(256);

  k_zero<<<256, blk, 0, stream>>>(W + OBAR, ZERO_SPAN_N);
  k_detect<<<1, blk, 0, stream>>>(flag, (const u16*)pnw1);
  k_prevw<<<64, blk, 0, stream>>>(W + OPRV, dlen);
  // dual-dtype setup (wrong variant self-disables via flag)
  k_mmat<false><<<64, blk, 0, stream>>>(flag, W + OMM, alocw, aconv);
  k_mmat<true ><<<64, blk, 0, stream>>>(flag, W + OMM, alocw, aconv);
  k_cvtT512<false><<<512, blk, 0, stream>>>(flag, W + OGI0, aencw);
  k_cvtT512<true ><<<512, blk, 0, stream>>>(flag, W + OGI0, aencw);
  k_pm<false><<<2048, blk, 0, stream>>>(flag, (u16*)(W + OPM), enc, W + OGI0, aencb);
  k_pm<true ><<<2048, blk, 0, stream>>>(flag, (u16*)(W + OPM), enc, W + OGI0, aencb);

  KP kp;
  kp.enc = enc; kp.dlen = dlen;
  kp.pm = (const u16*)(W + OPM);
  kp.wih0 = wih0; kp.whh0 = whh0;
  kp.wih1 = wih1; kp.whh1 = whh1;
  kp.adec = adecw; kp.outw = outw;
  kp.pnw2 = pnw2; kp.pnw1 = pnw1;
  kp.pnb1 = pnb1; kp.pnb2 = pnb2;
  kp.bih0 = bih0; kp.bhh0 = bhh0;
  kp.bih1 = bih1; kp.bhh1 = bhh1;
  kp.outb = outb; kp.vw = avw;
  kp.Mg = W + OMM;
  kp.bar = (int*)(W + OBAR);
  kp.flags = (int*)(W + OFLG);
  kp.asum = W + OASUM; kp.decp = W + ODEC;
  kp.h0T = W + OH0; kp.h1T = W + OH1;
  kp.poT0 = W + OPO; kp.poT1 = W + OPO + 10240;
  kp.prevw = W + OPRV; kp.erg = W + OERG;
  kp.x1T = W + OX1; kp.x2T = W + OX2;
  kp.attcT = W + OATTC; kp.attc2 = W + OATC2;
  kp.gi0p = W + OGI0; kp.gh0p = W + OGH0;
  kp.gh1p = W + OGH1; kp.gi1p = W + OGI1;
  kp.out = d_out;

  // both variants launched; the wrong-dtype one exits before touching the barrier
  k_loop<false><<<dim3(512), dim3(512), 0, stream>>>(kp);
  k_loop<true ><<<dim3(512), dim3(512), 0, stream>>>(kp);
}

// Round 10
// 86805.389 us; speedup vs baseline: 1.3663x; 1.3663x over previous
//
#include <hip/hip_runtime.h>
#include <hip/hip_bf16.h>

typedef unsigned short u16;
typedef float f32x4 __attribute__((ext_vector_type(4)));

// ---------------- constants ----------------
// B=64, T=512, C=512, H=512, D=80, RF=2, PRE_IN=160, PRE_INNER=256, CONV_CH=32, K=31

__device__ __forceinline__ float b2f(u16 u) {
  return __uint_as_float(((unsigned)u) << 16);
}
__device__ __forceinline__ u16 f2b(float f) {   // RNE f32->bf16
  unsigned u = __float_as_uint(f);
  u += 0x7fffu + ((u >> 16) & 1u);
  return (u16)(u >> 16);
}
template<bool F32>
__device__ __forceinline__ float ldw(const void* p, size_t i) {
  return F32 ? ((const float*)p)[i] : b2f(((const u16*)p)[i]);
}
template<bool F32>
__device__ __forceinline__ float4 ldw4(const void* p, size_t i) {
  if (F32) {
    return *(const float4*)((const float*)p + i);
  } else {
    uint2 u = *(const uint2*)((const u16*)p + i);
    float4 r;
    r.x = __uint_as_float(u.x << 16);
    r.y = __uint_as_float(u.x & 0xffff0000u);
    r.z = __uint_as_float(u.y << 16);
    r.w = __uint_as_float(u.y & 0xffff0000u);
    return r;
  }
}
template<bool F32>
__device__ __forceinline__ void stout(void* p, size_t i, float v) {
  if (F32) ((float*)p)[i] = v; else ((u16*)p)[i] = f2b(v);
}
__device__ __forceinline__ float frcp(float x) { return __builtin_amdgcn_rcpf(x); }
__device__ __forceinline__ float tanh_f(float x) {
  float e = __expf(2.f * x);
  return 1.f - 2.f * frcp(e + 1.f);     // inf-safe
}
__device__ __forceinline__ float sig_f(float x) { return frcp(1.f + __expf(-x)); }

// ---- relaxed agent-scope (MALL-coherent, fence-free) accessors ----
__device__ __forceinline__ void st_sc(int* p, int v) {
  __hip_atomic_store(p, v, __ATOMIC_RELAXED, __HIP_MEMORY_SCOPE_AGENT);
}
__device__ __forceinline__ int ld_sc(const int* p) {
  return __hip_atomic_load(p, __ATOMIC_RELAXED, __HIP_MEMORY_SCOPE_AGENT);
}
__device__ __forceinline__ void stf_sc(float* p, float v) {
  __hip_atomic_store(p, v, __ATOMIC_RELAXED, __HIP_MEMORY_SCOPE_AGENT);
}
__device__ __forceinline__ float ldf_sc(const float* p) {
  return __hip_atomic_load(p, __ATOMIC_RELAXED, __HIP_MEMORY_SCOPE_AGENT);
}

// ---- 16B agent-scope (L1/L2-bypassing, MALL-coherent) wide accessors ----
// Native ext-vector operands (f32x4): struct float4 is rejected as asm input.
// issue: no wait — batch many, then vm_wait0() before any use.
__device__ __forceinline__ void ld4_sc_issue(f32x4* dst, const float* p) {
  asm volatile("global_load_dwordx4 %0, %1, off sc0 sc1" : "=v"(*dst) : "v"(p));
}
__device__ __forceinline__ void vm_wait0() {
  asm volatile("s_waitcnt vmcnt(0)" ::: "memory");
  __builtin_amdgcn_sched_barrier(0);   // rule #18: fence reg-only consumers
}
__device__ __forceinline__ void st4_sc(float* p, f32x4 v) {
  asm volatile("global_store_dwordx4 %0, %1, off sc0 sc1" :: "v"(p), "v"(v) : "memory");
}

// Burst-copy NB*2048 floats global->LDS with NB dwordx4 loads in flight/thread.
template<int NB>
__device__ __forceinline__ void stage4(float* lds, const float* src, int tid) {
  f32x4 r[NB];
#pragma unroll
  for (int j = 0; j < NB; ++j) ld4_sc_issue(&r[j], src + j * 2048 + tid * 4);
  vm_wait0();
#pragma unroll
  for (int j = 0; j < NB; ++j) *(f32x4*)&lds[j * 2048 + tid * 4] = r[j];
}

// ---- software-pipelined weight-streaming dot kernel ----
template<bool F32, int NR>
__device__ __forceinline__ void dotN(float* __restrict__ acc, const float* __restrict__ sb,
                                     const void* __restrict__ wb, size_t rb, int wstride,
                                     int nk, int lane, int vz) {
  float4 wa[NR], wn[NR];
#pragma unroll
  for (int i = 0; i < NR; ++i) wa[i] = ldw4<F32>(wb, rb + (size_t)i * wstride + vz);
  for (int kg = 0; kg < nk; kg += 8) {
#pragma unroll
    for (int i = 0; i < NR; ++i) wn[i] = ldw4<F32>(wb, rb + (size_t)i * wstride + kg + 4 + vz);
    float a0 = sb[(kg + 0) * 64 + lane], a1 = sb[(kg + 1) * 64 + lane],
          a2 = sb[(kg + 2) * 64 + lane], a3 = sb[(kg + 3) * 64 + lane];
#pragma unroll
    for (int i = 0; i < NR; ++i)
      acc[i] = fmaf(wa[i].w, a3, fmaf(wa[i].z, a2, fmaf(wa[i].y, a1, fmaf(wa[i].x, a0, acc[i]))));
    int kn = (kg + 8 < nk) ? kg + 8 : kg;
#pragma unroll
    for (int i = 0; i < NR; ++i) wa[i] = ldw4<F32>(wb, rb + (size_t)i * wstride + kn + vz);
    float b0 = sb[(kg + 4) * 64 + lane], b1 = sb[(kg + 5) * 64 + lane],
          b2 = sb[(kg + 6) * 64 + lane], b3 = sb[(kg + 7) * 64 + lane];
#pragma unroll
    for (int i = 0; i < NR; ++i)
      acc[i] = fmaf(wn[i].w, b3, fmaf(wn[i].z, b2, fmaf(wn[i].y, b1, fmaf(wn[i].x, b0, acc[i]))));
  }
}

// ---------------- ws layout (float offsets), ~39.5 MB ----------------
constexpr size_t OBAR  = 0;                       // [32]=gen, [64]=dtype flag
constexpr size_t OFLG  = OBAR  + 128;             // per-wg arrival flags 256*32 ints
constexpr size_t OASUM = OFLG  + 8192;            // att_sum [b][t]     32768
constexpr size_t ODEC  = OASUM + 32768;           // dec0   [b][h]      32768
constexpr size_t OH0   = ODEC  + 32768;           // h0T    [h][b]      32768
constexpr size_t OH1   = OH0   + 32768;           // h1T    [h][b]      32768
constexpr size_t OPO   = OH1   + 32768;           // poT    [n][b]      10240
constexpr size_t OZEND = OPO   + 10240;
constexpr int    ZERO_SPAN_N = (int)OZEND;
constexpr size_t OPRV  = OZEND;                   // prev_w [b][t]      32768
constexpr size_t OERG  = OPRV  + 32768;           // erg    [b][t]      32768
constexpr size_t OX1   = OERG  + 32768;           // x1T    [n][b]      16384
constexpr size_t OX2   = OX1   + 16384;           // x2T    [n][b]      32768
constexpr size_t OATTC = OX2   + 32768;           // attcT  [c][b]      32768
constexpr size_t OMM   = OATTC + 32768;           // M[h][32] f32       16384
constexpr size_t OGI0  = OMM   + 16384;           // gi0p [4][1536][64] 393216 (setup alias: encT)
constexpr size_t OGH0  = OGI0  + 393216;          // gh0p               196608 (first 32768 double as dec1)
constexpr size_t OGH1  = OGH0  + 196608;          // gh1p               196608
constexpr size_t OGI1  = OGH1  + 196608;          // gi1p               393216
constexpr size_t OPM   = OGI1  + 393216;          // pmT bf16 [b][h][t] (16.7M u16)
constexpr size_t OTOT  = OPM   + 8388608;

// ---------------- fence-free flag barrier ----------------
__device__ __forceinline__ void fastbar(int* flags, int* gen, int target,
                                        int wg, int tid) {
  __syncthreads();
  if (tid == 0) st_sc(flags + wg * 32, target);
  if (wg == 0) {
    if (tid < 64) {
      int i0 = tid * 4;
      for (;;) {
        int ok = (ld_sc(flags + (i0 + 0) * 32) >= target)
               & (ld_sc(flags + (i0 + 1) * 32) >= target)
               & (ld_sc(flags + (i0 + 2) * 32) >= target)
               & (ld_sc(flags + (i0 + 3) * 32) >= target);
        if (__ballot(ok) == 0xFFFFFFFFFFFFFFFFull) break;
      }
      if (tid == 0) st_sc(gen, target);
    }
    __syncthreads();
  } else {
    if (tid == 0) {
      while (ld_sc(gen) < target) {}
    }
    __syncthreads();
  }
}

// ---------------- setup kernels (256 threads) ----------------
__global__ void k_zero(float* p, int n) {
  for (int i = blockIdx.x * 256 + threadIdx.x; i < n; i += gridDim.x * 256) p[i] = 0.f;
}
__global__ void k_detect(int* flag, const u16* probe) {
  if (blockIdx.x != 0 || threadIdx.x != 0) return;
  int sane = 0;
  for (int i = 0; i < 256; i += 2) {
    u16 u = probe[i];
    int e = (u >> 7) & 0xFF;
    if (u == 0 || (e >= 97 && e <= 140)) ++sane;
  }
  *flag = (sane < 96) ? 1 : 0;   // 1 => inputs are raw f32
}
__global__ void k_prevw(float* prevw, const int* dlen) {
  int b = blockIdx.x;
  int len = dlen[b] >> 1;
  float inv = 1.f / (float)len;
  for (int i = threadIdx.x; i < 512; i += 256)
    prevw[b * 512 + i] = (i < len) ? inv : 0.f;
}
template<bool F32>
__global__ void k_cvtT512(const int* flag, float* dst, const void* src) {
  if (*flag != (F32 ? 1 : 0)) return;
  for (int i = blockIdx.x * 256 + threadIdx.x; i < 262144; i += gridDim.x * 256) {
    int c = i >> 9, h = i & 511;
    dst[i] = ldw<F32>(src, (size_t)h * 512 + c);
  }
}
template<bool F32>
__global__ void k_mmat(const int* flag, float* M, const void* locw, const void* convw) {
  if (*flag != (F32 ? 1 : 0)) return;
  int i = blockIdx.x * 256 + threadIdx.x;
  if (i >= 16384) return;
  int h = i >> 5, k = i & 31;
  float acc = 0.f;
  if (k < 31) {
    for (int c = 0; c < 32; ++c)
      acc = fmaf(ldw<F32>(locw, h * 32 + c), ldw<F32>(convw, c * 31 + k), acc);
  }
  M[i] = acc;
}
// pm TRANSPOSED: pmT[b][h][t] so the decode loop reads 16 consecutive t per load
template<bool F32>
__global__ __launch_bounds__(256) void k_pm(const int* flag, u16* pm, const void* enc,
                                            const float* encwT, const void* encb) {
  if (*flag != (F32 ? 1 : 0)) return;
  __shared__ float encf[16 * 512];
  int row0 = blockIdx.x * 16;
  int tid = threadIdx.x;
  for (int i = tid; i < 16 * 512; i += 256) {
    int r = i >> 9, c = i & 511;
    encf[i] = ldw<F32>(enc, (size_t)(row0 + r) * 512 + c);
  }
  __syncthreads();
  float a0[16], a1[16];
  float bb0 = ldw<F32>(encb, tid), bb1 = ldw<F32>(encb, tid + 256);
#pragma unroll
  for (int r = 0; r < 16; ++r) { a0[r] = bb0; a1[r] = bb1; }
  for (int c = 0; c < 512; ++c) {
    float w0 = encwT[c * 512 + tid];
    float w1 = encwT[c * 512 + 256 + tid];
#pragma unroll
    for (int r = 0; r < 16; ++r) {
      float a = encf[r * 512 + c];
      a0[r] = fmaf(w0, a, a0[r]);
      a1[r] = fmaf(w1, a, a1[r]);
    }
  }
  int b = row0 >> 9, tl0 = row0 & 511;
  unsigned w0p[8], w1p[8];
#pragma unroll
  for (int rr = 0; rr < 8; ++rr) {
    w0p[rr] = (unsigned)f2b(a0[2 * rr]) | ((unsigned)f2b(a0[2 * rr + 1]) << 16);
    w1p[rr] = (unsigned)f2b(a1[2 * rr]) | ((unsigned)f2b(a1[2 * rr + 1]) << 16);
  }
  uint4* d0 = (uint4*)(pm + ((size_t)(b * 512 + tid)) * 512 + tl0);
  d0[0] = make_uint4(w0p[0], w0p[1], w0p[2], w0p[3]);
  d0[1] = make_uint4(w0p[4], w0p[5], w0p[6], w0p[7]);
  uint4* d1 = (uint4*)(pm + ((size_t)(b * 512 + 256 + tid)) * 512 + tl0);
  d1[0] = make_uint4(w1p[0], w1p[1], w1p[2], w1p[3]);
  d1[1] = make_uint4(w1p[4], w1p[5], w1p[6], w1p[7]);
}

// ---------------- main persistent kernel (256 wgs x 512 thr = 8 waves) ----------------
struct KP {
  const void* __restrict__ enc;
  const int* __restrict__ dlen;
  const u16* __restrict__ pm;          // internal bf16, TRANSPOSED [b][h][t]
  const void* __restrict__ wih0; const void* __restrict__ whh0;
  const void* __restrict__ wih1; const void* __restrict__ whh1;
  const void* __restrict__ adec; const void* __restrict__ outw;
  const void* __restrict__ pnw2; const void* __restrict__ pnw1;
  const void* __restrict__ pnb1; const void* __restrict__ pnb2;
  const void* __restrict__ bih0; const void* __restrict__ bhh0;
  const void* __restrict__ bih1; const void* __restrict__ bhh1;
  const void* __restrict__ outb; const void* __restrict__ vw;
  const float* __restrict__ Mg;
  int* __restrict__ bar;               // [32]=gen, [64]=dtype
  int* __restrict__ flags;             // 256 * 32 ints
  float* __restrict__ asum; float* __restrict__ dec;
  float* __restrict__ h0T;  float* __restrict__ h1T;  float* __restrict__ poT;
  float* __restrict__ prevw; float* __restrict__ erg;
  float* __restrict__ x1T;  float* __restrict__ x2T;  float* __restrict__ attcT;
  float* __restrict__ gi0p; float* __restrict__ gh0p;
  float* __restrict__ gh1p; float* __restrict__ gi1p;
  void* __restrict__ out;              // out_o at elem 0; out_a at elem 5242880
};

template<bool F32>
__global__ __launch_bounds__(512, 2) void k_loop(KP p) {
  if (*(const volatile int*)(p.bar + 64) != (F32 ? 1 : 0)) return;  // wrong-dtype variant exits
  __shared__ float stg[16384];       // 64 KB activation staging buffer
  __shared__ u16  M_u[32 * 512];
  __shared__ float dec_s[512];
  __shared__ float v_s[512];
  __shared__ float wq[160];
  __shared__ float sm[512];
  __shared__ float red[16];

  const int wg = blockIdx.x, tid = threadIdx.x;
  const int lane = tid & 63;
  const int wv = __builtin_amdgcn_readfirstlane(tid >> 6);   // 0..7
  const int b_att = wg >> 2, q = wg & 3, t0 = q * 128;
  const int trow = tid >> 6;          // 0..7 (= wv)
  const int hcol = tid & 63;
  float* dec1 = p.gh0p;              // dec partial 1 (region free between S4-read and S3-write)
  int* genp = p.bar + 32;
  int bt = 0;
  int vz;                            // opaque VGPR zero: forces VMEM path for weights
  asm volatile("v_mov_b32 %0, 0" : "=v"(vz));

  for (int i = tid; i < 32 * 512; i += 512) {
    int k = i >> 9, h = i & 511;
    M_u[i] = f2b(p.Mg[h * 32 + k]);
  }
  if (tid < 512) v_s[tid] = ldw<F32>(p.vw, tid);
  __syncthreads();

  for (int t = 0; t < 512; ++t) {
    // ===== S1: attention energies (+ prenet-1 from LDS-staged poT) =====
    if (wg < 32) stage4<5>(stg, p.poT, tid);        // poT [160][64] shared by 8 waves
    if (tid < 158) {
      int g = t0 - 15 + tid;
      wq[tid] = (g >= 0 && g < 512) ? ldf_sc(p.prevw + b_att * 512 + g) : 0.f;
    }
    if (tid < 128) {
      f32x4 da, db;
      ld4_sc_issue(&da, p.dec + b_att * 512 + tid * 4);
      ld4_sc_issue(&db, dec1 + b_att * 512 + tid * 4);
      vm_wait0();
      dec_s[tid * 4 + 0] = da[0] + db[0];
      dec_s[tid * 4 + 1] = da[1] + db[1];
      dec_s[tid * 4 + 2] = da[2] + db[2];
      dec_s[tid * 4 + 3] = da[3] + db[3];
    }
    __syncthreads();
    if (wg < 32) {                    // prenet-1: 32 wgs x 8 waves = 256 outputs
      int n = wg * 8 + wv;
      float a[1] = {0.f};
      dotN<F32, 1>(a, stg, p.pnw1, (size_t)n * 160, 160, 160, lane, vz);
      stf_sc(p.x1T + n * 64 + lane, fmaxf(a[0] + ldw<F32>(p.pnb1, n), 0.f));
    }
    {
      // each wave owns 16 s-rows; pm read TRANSPOSED: 16 t per dwordx4 pair
      float wreg[46];
#pragma unroll
      for (int i = 0; i < 46; ++i) wreg[i] = wq[trow * 16 + i];
      float acc[16];
#pragma unroll
      for (int s = 0; s < 16; ++s) acc[s] = 0.f;
      const u16* pmTb = p.pm + ((size_t)(b_att * 512)) * 512 + t0 + trow * 16;
      for (int j = 0; j < 8; ++j) {
        int hj = hcol + 64 * j;
        float Mreg[31];
#pragma unroll
        for (int k = 0; k < 31; ++k) Mreg[k] = b2f(M_u[k * 512 + hj]);
        float dj = dec_s[hj], vj = v_s[hj];
        const uint4* rp = (const uint4*)(pmTb + (size_t)hj * 512);
        uint4 q0 = rp[0], q1 = rp[1];
        unsigned qa[8] = {q0.x, q0.y, q0.z, q0.w, q1.x, q1.y, q1.z, q1.w};
#pragma unroll
        for (int s = 0; s < 16; ++s) {
          float u = dj;
#pragma unroll
          for (int k = 0; k < 31; ++k) u = fmaf(Mreg[k], wreg[s + k], u);
          unsigned wbits = qa[s >> 1];
          u += (s & 1) ? __uint_as_float(wbits & 0xffff0000u) : __uint_as_float(wbits << 16);
          acc[s] = fmaf(vj, tanh_f(u), acc[s]);
        }
      }
#pragma unroll
      for (int s = 0; s < 16; ++s) {
        float v = acc[s];
#pragma unroll
        for (int off = 32; off; off >>= 1) v += __shfl_xor(v, off, 64);
        if (hcol == 0) sm[trow * 16 + s] = v;
      }
      __syncthreads();
      if (tid < 128) stf_sc(p.erg + b_att * 512 + t0 + tid, sm[tid]);
    }
    fastbar(p.flags, genp, ++bt, wg, tid);

    // ===== S2: softmax/out_a | att_c (deep-ILP tau-split) | prenet-2 =====
    if (wg < 64) {
      int b = wg;
      int len = p.dlen[b] >> 1;
      float e0 = ldf_sc(p.erg + b * 512 + tid);
      bool v0 = tid < len;
      float mx = v0 ? e0 : -1e30f;
#pragma unroll
      for (int off = 32; off; off >>= 1) mx = fmaxf(mx, __shfl_xor(mx, off, 64));
      if (lane == 0) red[wv] = mx;
      __syncthreads();
      mx = fmaxf(fmaxf(fmaxf(red[0], red[1]), fmaxf(red[2], red[3])),
                 fmaxf(fmaxf(red[4], red[5]), fmaxf(red[6], red[7])));
      float x0 = v0 ? __expf(e0 - mx) : 0.f;
      float s = x0;
#pragma unroll
      for (int off = 32; off; off >>= 1) s += __shfl_xor(s, off, 64);
      if (lane == 0) red[8 + wv] = s;
      __syncthreads();
      s = ((red[8] + red[9]) + (red[10] + red[11])) + ((red[12] + red[13]) + (red[14] + red[15]));
      float w0 = x0 * frcp(s);
      stout<F32>(p.out, 5242880 + (size_t)b * 262144 + (size_t)tid * 512 + t, w0);
      float s0 = p.asum[b * 512 + tid] + w0;
      p.asum[b * 512 + tid] = s0;
      stf_sc(p.prevw + b * 512 + tid, s0);
    } else if (wg < 192) {
      int idx = wg - 64, b = idx >> 1, half = idx & 1;
      int len = p.dlen[b] >> 1;
      float e0 = ldf_sc(p.erg + b * 512 + tid);
      bool v0 = tid < len;
      float mx = v0 ? e0 : -1e30f;
#pragma unroll
      for (int off = 32; off; off >>= 1) mx = fmaxf(mx, __shfl_xor(mx, off, 64));
      if (lane == 0) red[wv] = mx;
      __syncthreads();
      mx = fmaxf(fmaxf(fmaxf(red[0], red[1]), fmaxf(red[2], red[3])),
                 fmaxf(fmaxf(red[4], red[5]), fmaxf(red[6], red[7])));
      float x0 = v0 ? __expf(e0 - mx) : 0.f;
      float s = x0;
#pragma unroll
      for (int off = 32; off; off >>= 1) s += __shfl_xor(s, off, 64);
      if (lane == 0) red[8 + wv] = s;
      __syncthreads();
      s = ((red[8] + red[9]) + (red[10] + red[11])) + ((red[12] + red[13]) + (red[14] + red[15]));
      sm[tid] = x0 * frcp(s);
      __syncthreads();
      // att_c: lane owns 4 consecutive channels; wave owns 64 taus, 16 chains
      int c4 = half * 256 + lane * 4;
      size_t eb = (size_t)b * 262144 + c4;
      float4 ac[16];
#pragma unroll
      for (int i = 0; i < 16; ++i) ac[i] = make_float4(0.f, 0.f, 0.f, 0.f);
      int tb = wv * 64;
      for (int tt = 0; tt < 64; tt += 16) {
#pragma unroll
        for (int i = 0; i < 16; ++i) {
          float4 e = ldw4<F32>(p.enc, eb + (size_t)(tb + tt + i) * 512);
          float w = sm[tb + tt + i];
          ac[i].x = fmaf(w, e.x, ac[i].x);
          ac[i].y = fmaf(w, e.y, ac[i].y);
          ac[i].z = fmaf(w, e.z, ac[i].z);
          ac[i].w = fmaf(w, e.w, ac[i].w);
        }
      }
      float4 ssum;
      ssum.x = 0.f; ssum.y = 0.f; ssum.z = 0.f; ssum.w = 0.f;
#pragma unroll
      for (int i = 0; i < 16; ++i) {
        ssum.x += ac[i].x; ssum.y += ac[i].y; ssum.z += ac[i].z; ssum.w += ac[i].w;
      }
      __syncthreads();                      // sm reads done before stg reuse
      *(float4*)&stg[wv * 256 + lane * 4] = ssum;   // 8 wave-partials x 256 ch
      __syncthreads();
      if (tid < 256) {
        float r = ((stg[tid] + stg[256 + tid]) + (stg[512 + tid] + stg[768 + tid]))
                + ((stg[1024 + tid] + stg[1280 + tid]) + (stg[1536 + tid] + stg[1792 + tid]));
        stf_sc(p.attcT + (half * 256 + tid) * 64 + b, r);
      }
    } else {
      stage4<8>(stg, p.x1T, tid);                // x1T [256][64] shared by 8 waves
      __syncthreads();
      int idx = wg - 192;                        // 64 wgs x 8 waves = 512 outputs
      int n = idx * 8 + wv;
      float a[1] = {0.f};
      dotN<F32, 1>(a, stg, p.pnw2, (size_t)n * 256, 256, 256, lane, vz);
      stf_sc(p.x2T + n * 64 + lane, fmaxf(a[0] + ldw<F32>(p.pnb2, n), 0.f));
    }
    fastbar(p.flags, genp, ++bt, wg, tid);

    // ===== S3: gi0 | gh0 | gh1 — wg stages one 64KB k-part; 8 waves share it =====
    {
      const float* src; const void* wb; float* dst;
      int n0, wstride, wc0;
      if (wg < 128) {               // gi0: kpart = wg&3, 32 n-groups of 48
        int kpart = wg & 3, ngrp = wg >> 2;
        src = ((kpart < 2) ? p.x2T : p.attcT) + (kpart & 1) * 16384;
        wb = p.wih0; wstride = 1024;
        wc0 = (kpart >> 1) * 512 + (kpart & 1) * 256;
        n0 = ngrp * 48 + wv * 6;
        dst = p.gi0p + ((size_t)kpart * 1536 + n0) * 64;
      } else if (wg < 192) {        // gh0
        int idx = wg - 128, kpart = idx & 1, ngrp = idx >> 1;
        src = p.h0T + kpart * 16384;
        wb = p.whh0; wstride = 512; wc0 = kpart * 256;
        n0 = ngrp * 48 + wv * 6;
        dst = p.gh0p + ((size_t)kpart * 1536 + n0) * 64;
      } else {                      // gh1
        int idx = wg - 192, kpart = idx & 1, ngrp = idx >> 1;
        src = p.h1T + kpart * 16384;
        wb = p.whh1; wstride = 512; wc0 = kpart * 256;
        n0 = ngrp * 48 + wv * 6;
        dst = p.gh1p + ((size_t)kpart * 1536 + n0) * 64;
      }
      stage4<8>(stg, src, tid);
      __syncthreads();
      float acc[6];
#pragma unroll
      for (int i = 0; i < 6; ++i) acc[i] = 0.f;
      dotN<F32, 6>(acc, stg, wb, (size_t)n0 * wstride + wc0, wstride, 256, lane, vz);
#pragma unroll
      for (int i = 0; i < 6; ++i) stf_sc(dst + (size_t)i * 64 + lane, acc[i]);
    }
    fastbar(p.flags, genp, ++bt, wg, tid);

    // ===== S4: GRU0 combine -> h0' (16 wgs, float4 across b) =====
    if (wg < 16) {
      int e = wg * 512 + tid;
      int h = e >> 4, b0 = (e & 15) * 4;
      f32x4 gi[12], gh[6], h0v;
#pragma unroll
      for (int c = 0; c < 4; ++c)
#pragma unroll
        for (int g3 = 0; g3 < 3; ++g3)
          ld4_sc_issue(&gi[c * 3 + g3], p.gi0p + ((size_t)c * 1536 + g3 * 512 + h) * 64 + b0);
#pragma unroll
      for (int c = 0; c < 2; ++c)
#pragma unroll
        for (int g3 = 0; g3 < 3; ++g3)
          ld4_sc_issue(&gh[c * 3 + g3], p.gh0p + ((size_t)c * 1536 + g3 * 512 + h) * 64 + b0);
      ld4_sc_issue(&h0v, p.h0T + h * 64 + b0);
      float bi_r = ldw<F32>(p.bih0, h), bi_z = ldw<F32>(p.bih0, 512 + h), bi_n = ldw<F32>(p.bih0, 1024 + h);
      float bh_r = ldw<F32>(p.bhh0, h), bh_z = ldw<F32>(p.bhh0, 512 + h), bh_n = ldw<F32>(p.bhh0, 1024 + h);
      vm_wait0();
      f32x4 outv;
#pragma unroll
      for (int qq = 0; qq < 4; ++qq) {
        float ir = bi_r + gi[0][qq] + gi[3][qq] + gi[6][qq] + gi[9][qq];
        float iz = bi_z + gi[1][qq] + gi[4][qq] + gi[7][qq] + gi[10][qq];
        float in = bi_n + gi[2][qq] + gi[5][qq] + gi[8][qq] + gi[11][qq];
        float hr = bh_r + gh[0][qq] + gh[3][qq];
        float hz = bh_z + gh[1][qq] + gh[4][qq];
        float hn = bh_n + gh[2][qq] + gh[5][qq];
        float r = sig_f(ir + hr), z = sig_f(iz + hz);
        float nn = tanh_f(in + r * hn);
        outv[qq] = (1.f - z) * nn + z * h0v[qq];
      }
      st4_sc(p.h0T + h * 64 + b0, outv);
    }
    fastbar(p.flags, genp, ++bt, wg, tid);

    // ===== S5: gi1 | dec partials (both halves in parallel) =====
    if (wg < 128) {                 // gi1: kpart = wg&3 (128-wide), 32 n-groups of 48
      int kpart = wg & 3, ngrp = wg >> 2;
      stage4<4>(stg, p.h0T + kpart * 8192, tid);
      __syncthreads();
      int n0 = ngrp * 48 + wv * 6;
      float acc[6];
#pragma unroll
      for (int i = 0; i < 6; ++i) acc[i] = 0.f;
      dotN<F32, 6>(acc, stg, p.wih1, (size_t)n0 * 512 + kpart * 128, 512, 128, lane, vz);
#pragma unroll
      for (int i = 0; i < 6; ++i)
        stf_sc(p.gi1p + ((size_t)kpart * 1536 + n0 + i) * 64 + lane, acc[i]);
    } else {                        // dec partials: wgs 128-191 -> chunk0, 192-255 -> chunk1
      int g = wg - 128;
      int cpart = g >> 6;
      int n = (g & 63) * 8 + wv;                 // one output per wave
      stage4<8>(stg, p.h0T + cpart * 16384, tid);
      __syncthreads();
      float r[1] = {0.f};
      dotN<F32, 1>(r, stg, p.adec, (size_t)n * 512 + cpart * 256, 512, 256, lane, vz);
      float* dst = cpart ? dec1 : p.dec;
      stf_sc(dst + lane * 512 + n, r[0]);
    }
    fastbar(p.flags, genp, ++bt, wg, tid);

    // ===== S6: GRU1 combine -> h1' (16 wgs, float4 across b) =====
    if (wg < 16) {
      int e = wg * 512 + tid;
      int h = e >> 4, b0 = (e & 15) * 4;
      f32x4 gi[12], gh[6], h1v;
#pragma unroll
      for (int c = 0; c < 4; ++c)
#pragma unroll
        for (int g3 = 0; g3 < 3; ++g3)
          ld4_sc_issue(&gi[c * 3 + g3], p.gi1p + ((size_t)c * 1536 + g3 * 512 + h) * 64 + b0);
#pragma unroll
      for (int c = 0; c < 2; ++c)
#pragma unroll
        for (int g3 = 0; g3 < 3; ++g3)
          ld4_sc_issue(&gh[c * 3 + g3], p.gh1p + ((size_t)c * 1536 + g3 * 512 + h) * 64 + b0);
      ld4_sc_issue(&h1v, p.h1T + h * 64 + b0);
      float bi_r = ldw<F32>(p.bih1, h), bi_z = ldw<F32>(p.bih1, 512 + h), bi_n = ldw<F32>(p.bih1, 1024 + h);
      float bh_r = ldw<F32>(p.bhh1, h), bh_z = ldw<F32>(p.bhh1, 512 + h), bh_n = ldw<F32>(p.bhh1, 1024 + h);
      vm_wait0();
      f32x4 outv;
#pragma unroll
      for (int qq = 0; qq < 4; ++qq) {
        float ir = bi_r + gi[0][qq] + gi[3][qq] + gi[6][qq] + gi[9][qq];
        float iz = bi_z + gi[1][qq] + gi[4][qq] + gi[7][qq] + gi[10][qq];
        float in = bi_n + gi[2][qq] + gi[5][qq] + gi[8][qq] + gi[11][qq];
        float hr = bh_r + gh[0][qq] + gh[3][qq];
        float hz = bh_z + gh[1][qq] + gh[4][qq];
        float hn = bh_n + gh[2][qq] + gh[5][qq];
        float r = sig_f(ir + hr), z = sig_f(iz + hz);
        float nn = tanh_f(in + r * hn);
        outv[qq] = (1.f - z) * nn + z * h1v[qq];
      }
      st4_sc(p.h1T + h * 64 + b0, outv);
    }
    fastbar(p.flags, genp, ++bt, wg, tid);

    // ===== S7: out = Wout @ [h1' ; att_c] + b — chunked LDS staging =====
    if (wg < 20) {
      int n = wg * 8 + wv;                       // 20 wgs x 8 waves = 160 outputs
      float r[1] = {0.f};
      for (int c = 0; c < 4; ++c) {
        const float* src = ((c < 2) ? p.h1T : p.attcT) + (c & 1) * 16384;
        stage4<8>(stg, src, tid);
        __syncthreads();
        dotN<F32, 1>(r, stg, p.outw, (size_t)n * 1024 + c * 256, 1024, 256, lane, vz);
        __syncthreads();
      }
      float acc = r[0] + ldw<F32>(p.outb, n);
      stf_sc(p.poT + n * 64 + lane, acc);
      stout<F32>(p.out, (size_t)lane * 81920 + (size_t)(n >> 1) * 1024 + t * 2 + (n & 1), acc);
    }
    fastbar(p.flags, genp, ++bt, wg, tid);
  }
}

// ---------------- host launcher ----------------
extern "C" void kernel_launch(void* const* d_in, const int* in_sizes, int n_in,
                              void* d_out, int out_size, void* d_ws, size_t ws_size,
                              hipStream_t stream) {
  (void)in_sizes; (void)n_in; (void)out_size; (void)ws_size;
  const void* enc   = d_in[0];
  const int*  dlen  = (const int*)d_in[1];
  const void* pnw1  = d_in[2];
  const void* pnb1  = d_in[3];
  const void* pnw2  = d_in[4];
  const void* pnb2  = d_in[5];
  const void* aencw = d_in[6];
  const void* aencb = d_in[7];
  const void* adecw = d_in[8];
  const void* aconv = d_in[9];
  const void* alocw = d_in[10];
  const void* avw   = d_in[11];
  // d_in[12] = att_v_b: softmax-invariant -> unused
  const void* wih0  = d_in[13];
  const void* whh0  = d_in[14];
  const void* bih0  = d_in[15];
  const void* bhh0  = d_in[16];
  const void* wih1  = d_in[17];
  const void* whh1  = d_in[18];
  const void* bih1  = d_in[19];
  const void* bhh1  = d_in[20];
  const void* outw  = d_in[21];
  const void* outb  = d_in[22];

  float* W = (float*)d_ws;
  int* flag = (int*)(W + OBAR) + 64;
  dim3 blk(256);

  k_zero<<<256, blk, 0, stream>>>(W + OBAR, ZERO_SPAN_N);
  k_zero<<<64, blk, 0, stream>>>(W + OGH0, 32768);   // dec1 initial zero
  k_detect<<<1, blk, 0, stream>>>(flag, (const u16*)pnw1);
  k_prevw<<<64, blk, 0, stream>>>(W + OPRV, dlen);
  // dual-dtype setup (wrong variant self-disables via flag)
  k_mmat<false><<<64, blk, 0, stream>>>(flag, W + OMM, alocw, aconv);
  k_mmat<true ><<<64, blk, 0, stream>>>(flag, W + OMM, alocw, aconv);
  k_cvtT512<false><<<512, blk, 0, stream>>>(flag, W + OGI0, aencw);
  k_cvtT512<true ><<<512, blk, 0, stream>>>(flag, W + OGI0, aencw);
  k_pm<false><<<2048, blk, 0, stream>>>(flag, (u16*)(W + OPM), enc, W + OGI0, aencb);
  k_pm<true ><<<2048, blk, 0, stream>>>(flag, (u16*)(W + OPM), enc, W + OGI0, aencb);

  KP kp;
  kp.enc = enc; kp.dlen = dlen;
  kp.pm = (const u16*)(W + OPM);
  kp.wih0 = wih0; kp.whh0 = whh0;
  kp.wih1 = wih1; kp.whh1 = whh1;
  kp.adec = adecw; kp.outw = outw;
  kp.pnw2 = pnw2; kp.pnw1 = pnw1;
  kp.pnb1 = pnb1; kp.pnb2 = pnb2;
  kp.bih0 = bih0; kp.bhh0 = bhh0;
  kp.bih1 = bih1; kp.bhh1 = bhh1;
  kp.outb = outb; kp.vw = avw;
  kp.Mg = W + OMM;
  kp.bar = (int*)(W + OBAR);
  kp.flags = (int*)(W + OFLG);
  kp.asum = W + OASUM; kp.dec = W + ODEC;
  kp.h0T = W + OH0; kp.h1T = W + OH1; kp.poT = W + OPO;
  kp.prevw = W + OPRV; kp.erg = W + OERG;
  kp.x1T = W + OX1; kp.x2T = W + OX2; kp.attcT = W + OATTC;
  kp.gi0p = W + OGI0; kp.gh0p = W + OGH0;
  kp.gh1p = W + OGH1; kp.gi1p = W + OGI1;
  kp.out = d_out;

  // both variants launched; the wrong-dtype one exits before touching the barrier
  k_loop<false><<<dim3(256), dim3(512), 0, stream>>>(kp);
  k_loop<true ><<<dim3(256), dim3(512), 0, stream>>>(kp);
}